// Round 1
// baseline (14288.289 us; speedup 1.0000x reference)
//
#include <hip/hip_runtime.h>
#include <hip/hip_bf16.h>
#include <math.h>

// Problem dims
#define EE   512
#define HJ   1024      // decoder hidden H
#define HH2  512       // encoder hidden HH
#define VV   32000
#define BB   32
#define SS   48
#define TT   48

typedef float f32x4 __attribute__((ext_vector_type(4)));
typedef __bf16 bf16x8 __attribute__((ext_vector_type(8)));
typedef __bf16 bf16x4 __attribute__((ext_vector_type(4)));

// ---------------------------------------------------------------- embeddings
__global__ void embed_src_kernel(const float* __restrict__ enc_embed,
                                 const int* __restrict__ src_tokens,
                                 const int* __restrict__ src_lengths,
                                 __bf16* __restrict__ emb, __bf16* __restrict__ embR) {
  int idx = blockIdx.x * 256 + threadIdx.x;
  if (idx >= BB * SS * EE) return;
  int e = idx & (EE - 1);
  int bs = idx >> 9;            // E=512
  int b = bs / SS, s = bs % SS;
  int tok = src_tokens[b * SS + s];
  emb[idx] = (__bf16)enc_embed[(size_t)tok * EE + e];
  int len = src_lengths[b];
  int rs = len - 1 - s; if (rs < 0) rs = 0;
  int tokr = src_tokens[b * SS + rs];
  embR[idx] = (__bf16)enc_embed[(size_t)tokr * EE + e];
}

__global__ void embed_tgt_kernel(const float* __restrict__ dec_embed,
                                 const int* __restrict__ tgt_tokens,
                                 __bf16* __restrict__ demb) {
  int idx = blockIdx.x * 256 + threadIdx.x;
  if (idx >= BB * TT * EE) return;
  int e = idx & (EE - 1);
  int bt = idx >> 9;
  int b = bt / TT, t = bt % TT;
  int tok = tgt_tokens[b * (TT + 1) + t];       // tgt_in = tgt[:, :-1]
  demb[idx] = (__bf16)dec_embed[(size_t)tok * EE + e];
}

// ---------------------------------------------------------------- converts
__global__ void f2bf_kernel(const float* __restrict__ src, __bf16* __restrict__ dst, int n4) {
  int i = blockIdx.x * 256 + threadIdx.x;
  if (i >= n4) return;
  float4 v = ((const float4*)src)[i];
  bf16x4 p = {(__bf16)v.x, (__bf16)v.y, (__bf16)v.z, (__bf16)v.w};
  ((bf16x4*)dst)[i] = p;
}

__global__ void f2bf_slice_kernel(const float* __restrict__ src, __bf16* __restrict__ dst,
                                  int rows, int cols, int ld, int c0) {
  int idx = blockIdx.x * 256 + threadIdx.x;
  if (idx >= rows * cols) return;
  int r = idx / cols, cc = idx % cols;
  dst[idx] = (__bf16)src[(size_t)r * ld + c0 + cc];
}

// ---------------------------------------------------------------- transpose (fp32)
// dst[c*R + r] = src[r*ld + c0 + c], r<R, c<C ; R,C multiples of 32
__global__ void transpose_kernel(const float* __restrict__ src, float* __restrict__ dst,
                                 int R, int C, int ld, int c0) {
  __shared__ float tile[32][33];
  int cb = blockIdx.x * 32, rb = blockIdx.y * 32;
  int tx = threadIdx.x & 31, ty = threadIdx.x >> 5;   // 32x8
  for (int i = ty; i < 32; i += 8)
    tile[i][tx] = src[(size_t)(rb + i) * ld + c0 + cb + tx];
  __syncthreads();
  for (int i = ty; i < 32; i += 8)
    dst[(size_t)(cb + i) * R + rb + tx] = tile[tx][i];
}

// ---------------------------------------------------------------- bf16 MFMA GEMM (NT)
// C[m][n] = sum_k A[m][k]*B[n][k] + bias1[n] + bias2[n]
// A: M x K bf16 (M=1536), B: N x K bf16. Tile 128x128, BK=32. grid (M/128, N/128)
__global__ __launch_bounds__(256) void gemm_bf16_kernel(
    const __bf16* __restrict__ A, const __bf16* __restrict__ Bm,
    const float* __restrict__ bias1, const float* __restrict__ bias2,
    float* __restrict__ C, int K, int N) {
  const int m0 = blockIdx.x * 128;
  const int n0 = blockIdx.y * 128;
  __shared__ __bf16 As[128 * 40];
  __shared__ __bf16 Bs[128 * 40];
  const int tid = threadIdx.x;
  const int lane = tid & 63, wave = tid >> 6;
  const int wm = (wave >> 1) * 64, wn = (wave & 1) * 64;
  const f32x4 zero = {0.f, 0.f, 0.f, 0.f};
  f32x4 acc[4][4];
  for (int i = 0; i < 4; i++) for (int j = 0; j < 4; j++) acc[i][j] = zero;
  const int r = tid >> 2, seg = tid & 3;
  const int mr = lane & 15, q8 = (lane >> 4) * 8;
  for (int k0 = 0; k0 < K; k0 += 32) {
    *(float4*)&As[r * 40 + seg * 8]        = *(const float4*)&A[(size_t)(m0 + r) * K + k0 + seg * 8];
    *(float4*)&As[(r + 64) * 40 + seg * 8] = *(const float4*)&A[(size_t)(m0 + r + 64) * K + k0 + seg * 8];
    *(float4*)&Bs[r * 40 + seg * 8]        = *(const float4*)&Bm[(size_t)(n0 + r) * K + k0 + seg * 8];
    *(float4*)&Bs[(r + 64) * 40 + seg * 8] = *(const float4*)&Bm[(size_t)(n0 + r + 64) * K + k0 + seg * 8];
    __syncthreads();
    bf16x8 af[4], bfr[4];
    for (int i = 0; i < 4; i++) af[i]  = *(const bf16x8*)&As[(wm + i * 16 + mr) * 40 + q8];
    for (int i = 0; i < 4; i++) bfr[i] = *(const bf16x8*)&Bs[(wn + i * 16 + mr) * 40 + q8];
    for (int i = 0; i < 4; i++)
      for (int j = 0; j < 4; j++)
        acc[i][j] = __builtin_amdgcn_mfma_f32_16x16x32_bf16(af[i], bfr[j], acc[i][j], 0, 0, 0);
    __syncthreads();
  }
  const int col = lane & 15, q = lane >> 4;
  for (int i = 0; i < 4; i++) {
    int rowg = m0 + wm + i * 16 + q * 4;
    for (int j = 0; j < 4; j++) {
      int cg = n0 + wn + j * 16 + col;
      float bb = bias1[cg] + bias2[cg];
      for (int rr = 0; rr < 4; rr++)
        C[(size_t)(rowg + rr) * N + cg] = acc[i][j][rr] + bb;
    }
  }
}

// ---------------------------------------------------------------- logits MFMA + exp-sum epilogue
// A: outs_bf (1536 x 2048). B: Ws_W fp32 (32000 x 2048), converted to bf16 in staging.
// rowsum[m] += sum_n exp(logit[m][n] + Ws_b[n]).  grid (12, 250), x = m fastest for B-tile reuse.
__global__ __launch_bounds__(256) void logits_kernel(
    const __bf16* __restrict__ A, const float* __restrict__ WsW,
    const float* __restrict__ Wsb, float* __restrict__ rowsum) {
  const int m0 = blockIdx.x * 128;
  const int n0 = blockIdx.y * 128;
  __shared__ __bf16 As[128 * 40];
  __shared__ __bf16 Bs[128 * 40];
  const int tid = threadIdx.x;
  const int lane = tid & 63, wave = tid >> 6;
  const int wm = (wave >> 1) * 64, wn = (wave & 1) * 64;
  const f32x4 zero = {0.f, 0.f, 0.f, 0.f};
  f32x4 acc[4][4];
  for (int i = 0; i < 4; i++) for (int j = 0; j < 4; j++) acc[i][j] = zero;
  const int r = tid >> 2, seg = tid & 3;
  const int rowb = tid >> 1, koff = (tid & 1) * 16;
  const int mr = lane & 15, q8 = (lane >> 4) * 8;
  for (int k0 = 0; k0 < 2048; k0 += 32) {
    *(float4*)&As[r * 40 + seg * 8]        = *(const float4*)&A[(size_t)(m0 + r) * 2048 + k0 + seg * 8];
    *(float4*)&As[(r + 64) * 40 + seg * 8] = *(const float4*)&A[(size_t)(m0 + r + 64) * 2048 + k0 + seg * 8];
    const float* gb = WsW + (size_t)(n0 + rowb) * 2048 + k0 + koff;
    float4 v0 = *(const float4*)(gb);
    float4 v1 = *(const float4*)(gb + 4);
    float4 v2 = *(const float4*)(gb + 8);
    float4 v3 = *(const float4*)(gb + 12);
    bf16x8 p0 = {(__bf16)v0.x,(__bf16)v0.y,(__bf16)v0.z,(__bf16)v0.w,
                 (__bf16)v1.x,(__bf16)v1.y,(__bf16)v1.z,(__bf16)v1.w};
    bf16x8 p1 = {(__bf16)v2.x,(__bf16)v2.y,(__bf16)v2.z,(__bf16)v2.w,
                 (__bf16)v3.x,(__bf16)v3.y,(__bf16)v3.z,(__bf16)v3.w};
    *(bf16x8*)&Bs[rowb * 40 + koff]     = p0;
    *(bf16x8*)&Bs[rowb * 40 + koff + 8] = p1;
    __syncthreads();
    bf16x8 af[4], bfr[4];
    for (int i = 0; i < 4; i++) af[i]  = *(const bf16x8*)&As[(wm + i * 16 + mr) * 40 + q8];
    for (int i = 0; i < 4; i++) bfr[i] = *(const bf16x8*)&Bs[(wn + i * 16 + mr) * 40 + q8];
    for (int i = 0; i < 4; i++)
      for (int j = 0; j < 4; j++)
        acc[i][j] = __builtin_amdgcn_mfma_f32_16x16x32_bf16(af[i], bfr[j], acc[i][j], 0, 0, 0);
    __syncthreads();
  }
  const int col = lane & 15, q = lane >> 4;
  for (int i = 0; i < 4; i++) {
    float s0 = 0, s1 = 0, s2 = 0, s3 = 0;
    for (int j = 0; j < 4; j++) {
      int cg = n0 + wn + j * 16 + col;
      float bb = Wsb[cg];
      s0 += expf(acc[i][j][0] + bb);
      s1 += expf(acc[i][j][1] + bb);
      s2 += expf(acc[i][j][2] + bb);
      s3 += expf(acc[i][j][3] + bb);
    }
    for (int off = 1; off < 16; off <<= 1) {
      s0 += __shfl_xor(s0, off, 64);
      s1 += __shfl_xor(s1, off, 64);
      s2 += __shfl_xor(s2, off, 64);
      s3 += __shfl_xor(s3, off, 64);
    }
    if (col == 0) {
      int rowg = m0 + wm + i * 16 + q * 4;
      atomicAdd(&rowsum[rowg],     s0);
      atomicAdd(&rowsum[rowg + 1], s1);
      atomicAdd(&rowsum[rowg + 2], s2);
      atomicAdd(&rowsum[rowg + 3], s3);
    }
  }
}

// ---------------------------------------------------------------- encoder step (both dirs)
// grid (32 uchunks, 4 bgroups, 2 dirs), 256 thr. gates += h @ WhhT; fused cell update.
__global__ __launch_bounds__(256) void enc_step_kernel(
    const float* __restrict__ xg,    // [2][B*S*2048] precomputed x@Wih^T + biases
    const float* __restrict__ WhhT,  // [2][512*2048] k-major
    const float* __restrict__ h_in,  // [2][B*512]
    float* __restrict__ h_out,       // [2][B*512]
    float* __restrict__ c,           // [2][B*512]
    float* __restrict__ outbuf,      // [2][B*S*512]
    const int* __restrict__ src_lengths, int t) {
  const int u0 = blockIdx.x * 16;
  const int b0 = blockIdx.y * 8;
  const int d  = blockIdx.z;
  const float* xgd = xg + (size_t)d * (BB * SS * 2048);
  const float* WT  = WhhT + (size_t)d * (512 * 2048);
  const float* hi  = h_in + d * (BB * 512);
  float* ho = h_out + d * (BB * 512);
  float* cd = c + d * (BB * 512);
  float* ob = outbuf + (size_t)d * (BB * SS * 512);
  __shared__ float hl[8 * 512];
  __shared__ float gl[8 * 64];
  const int tid = threadIdx.x;
  for (int i = tid; i < 8 * 512; i += 256) {
    int bi = i >> 9, k = i & 511;
    hl[i] = hi[(b0 + bi) * 512 + k];
  }
  __syncthreads();
  const int lane = tid & 63, bq = tid >> 6;
  const int g = lane >> 4, u = lane & 15;
  const int j = g * 512 + u0 + u;
  const int ba = b0 + bq * 2;
  float acc0 = xgd[((size_t)ba * SS + t) * 2048 + j];
  float acc1 = xgd[((size_t)(ba + 1) * SS + t) * 2048 + j];
  const float* ha = hl + (bq * 2) * 512;
  const float* hb = ha + 512;
  const float* wp = WT + j;
#pragma unroll 4
  for (int k = 0; k < 512; k++) {
    float w = wp[(size_t)k * 2048];
    acc0 += ha[k] * w;
    acc1 += hb[k] * w;
  }
  gl[(bq * 2) * 64 + lane]     = acc0;
  gl[(bq * 2 + 1) * 64 + lane] = acc1;
  __syncthreads();
  if (tid < 128) {
    int bi = tid >> 4, uu = tid & 15;
    int b = b0 + bi;
    float gi = gl[bi * 64 + uu],      gf = gl[bi * 64 + 16 + uu];
    float gg = gl[bi * 64 + 32 + uu], go = gl[bi * 64 + 48 + uu];
    int idx = b * 512 + u0 + uu;
    float cold = cd[idx];
    float hold = hl[bi * 512 + u0 + uu];
    float si = 1.f / (1.f + expf(-gi)), sf = 1.f / (1.f + expf(-gf)), so = 1.f / (1.f + expf(-go));
    float cn = sf * cold + si * tanhf(gg);
    float hn = so * tanhf(cn);
    bool m = t < src_lengths[b];
    cd[idx] = m ? cn : cold;
    ho[idx] = m ? hn : hold;
    ob[((size_t)b * SS + t) * 512 + u0 + uu] = m ? hn : 0.f;
  }
}

// ---------------------------------------------------------------- compose src_enc + decoder init
__global__ void compose_kernel(const float* __restrict__ out_f, const float* __restrict__ out_r,
                               const float* __restrict__ henc, const float* __restrict__ cenc,
                               const int* __restrict__ src_lengths,
                               float* __restrict__ src_enc, float* __restrict__ hdec,
                               float* __restrict__ cdec) {
  int idx = blockIdx.x * 256 + threadIdx.x;
  const int N1 = BB * SS * HJ;                  // 1536*1024
  if (idx < N1) {
    int u = idx & 1023;
    int bs = idx >> 10;
    int b = bs / SS, s = bs % SS;
    float v;
    if (u < 512) v = out_f[((size_t)b * SS + s) * 512 + u];
    else {
      int len = src_lengths[b];
      int rs = len - 1 - s; if (rs < 0) rs = 0;
      v = (s < len) ? out_r[((size_t)b * SS + rs) * 512 + (u - 512)] : 0.f;
    }
    src_enc[idx] = v;
  } else if (idx < N1 + 2 * BB * HJ) {
    int k = idx - N1;
    int u = k & 1023;
    int bh = k >> 10;
    int b = bh & 31, which = bh >> 5;           // 0: h, 1: c
    const float* s = which ? cenc : henc;       // [2][B*512]
    float v = (u < 512) ? s[b * 512 + u] : s[BB * 512 + b * 512 + (u - 512)];
    if (which) cdec[b * HJ + u] = v; else hdec[b * HJ + u] = v;
  }
}

// ---------------------------------------------------------------- decoder step (gates+cell)
// grid (64 uchunks, 4 bgroups), 256 thr. x = [wa, h] (K=2048 concat), WT = [dWihT_wa ; dWhhT]
__global__ __launch_bounds__(256) void dec_step_kernel(
    const float* __restrict__ pre,   // [B*T*4096] emb@Wih_emb^T + biases
    const float* __restrict__ WT,    // [2048 * 4096] k-major
    const float* __restrict__ wav,   // [B*1024]
    const float* __restrict__ h_in,  // [B*1024]
    float* __restrict__ h_out,
    float* __restrict__ c,           // [B*1024]
    int t) {
  __shared__ float xl[8 * 2048];
  __shared__ float gl[8 * 64];
  const int tid = threadIdx.x;
  const int u0 = blockIdx.x * 16;
  const int b0 = blockIdx.y * 8;
  for (int i = tid; i < 8 * 2048; i += 256) {
    int bi = i >> 11, k = i & 2047;
    int b = b0 + bi;
    xl[i] = (k < 1024) ? wav[b * 1024 + k] : h_in[b * 1024 + (k - 1024)];
  }
  __syncthreads();
  const int lane = tid & 63, bq = tid >> 6;
  const int g = lane >> 4, u = lane & 15;
  const int j = g * 1024 + u0 + u;
  const int ba = b0 + bq * 2;
  float acc0 = pre[((size_t)ba * TT + t) * 4096 + j];
  float acc1 = pre[((size_t)(ba + 1) * TT + t) * 4096 + j];
  const float* xa = xl + (bq * 2) * 2048;
  const float* xb = xa + 2048;
  const float* wp = WT + j;
#pragma unroll 4
  for (int k = 0; k < 2048; k++) {
    float w = wp[(size_t)k * 4096];
    acc0 += xa[k] * w;
    acc1 += xb[k] * w;
  }
  gl[(bq * 2) * 64 + lane]     = acc0;
  gl[(bq * 2 + 1) * 64 + lane] = acc1;
  __syncthreads();
  if (tid < 128) {
    int bi = tid >> 4, uu = tid & 15;
    int b = b0 + bi;
    float gi = gl[bi * 64 + uu],      gf = gl[bi * 64 + 16 + uu];
    float gg = gl[bi * 64 + 32 + uu], go = gl[bi * 64 + 48 + uu];
    int idx = b * 1024 + u0 + uu;
    float cold = c[idx];
    float si = 1.f / (1.f + expf(-gi)), sf = 1.f / (1.f + expf(-gf)), so = 1.f / (1.f + expf(-go));
    float cn = sf * cold + si * tanhf(gg);
    float hn = so * tanhf(cn);
    c[idx] = cn;
    h_out[idx] = hn;
  }
}

// ---------------------------------------------------------------- decoder attention
// grid 32 (b), 256 thr. align -> masked softmax -> wa; writes wa and outs_bf row t.
__global__ __launch_bounds__(256) void dec_attn_kernel(
    const float* __restrict__ h,        // [B*1024] (new h)
    const float* __restrict__ src_enc,  // [B*S*1024]
    const int* __restrict__ src_lengths,
    float* __restrict__ wa,             // [B*1024]
    __bf16* __restrict__ outs_bf,       // [B*T*2048]
    int t) {
  const int b = blockIdx.x;
  __shared__ float hl[1024];
  __shared__ float al[64];
  const int tid = threadIdx.x;
  for (int i = tid; i < 1024; i += 256) hl[i] = h[b * 1024 + i];
  __syncthreads();
  const int wave = tid >> 6, lane = tid & 63;
  for (int si = 0; si < 12; si++) {
    int s = wave * 12 + si;
    const float* row = src_enc + ((size_t)b * SS + s) * 1024;
    float p = 0;
    for (int kk = lane; kk < 1024; kk += 64) p += row[kk] * hl[kk];
    for (int off = 32; off > 0; off >>= 1) p += __shfl_down(p, off, 64);
    if (lane == 0) al[s] = p;
  }
  __syncthreads();
  if (wave == 0) {
    int len = src_lengths[b];
    bool valid = (lane < SS) && (lane < len);
    float a = valid ? al[lane] : -1e30f;
    float mx = a;
    for (int off = 32; off > 0; off >>= 1) mx = fmaxf(mx, __shfl_xor(mx, off, 64));
    float p = valid ? expf(a - mx) : 0.f;
    float sm = p;
    for (int off = 32; off > 0; off >>= 1) sm += __shfl_xor(sm, off, 64);
    if (lane < SS) al[lane] = p / sm;
  }
  __syncthreads();
  for (int jj = tid; jj < 1024; jj += 256) {
    float w = 0;
    for (int s = 0; s < SS; s++) w += al[s] * src_enc[((size_t)b * SS + s) * 1024 + jj];
    wa[b * 1024 + jj] = w;
    size_t orow = ((size_t)b * TT + t) * 2048;
    outs_bf[orow + jj] = (__bf16)w;
    outs_bf[orow + 1024 + jj] = (__bf16)hl[jj];
  }
}

// ---------------------------------------------------------------- target logit per row
__global__ __launch_bounds__(256) void tgt_logit_kernel(
    const __bf16* __restrict__ outs_bf, const float* __restrict__ WsW,
    const float* __restrict__ Wsb, const int* __restrict__ tgt_tokens,
    float* __restrict__ tlogit) {
  const int r = blockIdx.x;
  const int b = r / TT, t = r % TT;
  const int tgt = tgt_tokens[b * (TT + 1) + t + 1];
  const __bf16* a = outs_bf + (size_t)r * 2048;
  const float* w = WsW + (size_t)tgt * 2048;
  const int tid = threadIdx.x;
  float p = 0;
  for (int k = tid; k < 2048; k += 256) p += (float)a[k] * w[k];
  for (int off = 32; off > 0; off >>= 1) p += __shfl_down(p, off, 64);
  __shared__ float red[4];
  if ((tid & 63) == 0) red[tid >> 6] = p;
  __syncthreads();
  if (tid == 0) tlogit[r] = red[0] + red[1] + red[2] + red[3] + Wsb[tgt];
}

// ---------------------------------------------------------------- final reduce
__global__ void final_kernel(const float* __restrict__ rowsum, const float* __restrict__ tlogit,
                             const int* __restrict__ tgt_tokens, float* __restrict__ out) {
  const int tid = threadIdx.x;
  float s = 0;
  for (int r = tid; r < BB * TT; r += 256) {
    int b = r / TT, t = r % TT;
    int tgt = tgt_tokens[b * (TT + 1) + t + 1];
    if (tgt != 0) s += logf(rowsum[r]) - tlogit[r];
  }
  for (int off = 32; off > 0; off >>= 1) s += __shfl_down(s, off, 64);
  __shared__ float red[4];
  if ((tid & 63) == 0) red[tid >> 6] = s;
  __syncthreads();
  if (tid == 0) out[0] = red[0] + red[1] + red[2] + red[3];
}

// ================================================================ host
extern "C" void kernel_launch(void* const* d_in, const int* in_sizes, int n_in,
                              void* d_out, int out_size, void* d_ws, size_t ws_size,
                              hipStream_t stream) {
  const float* enc_embed = (const float*)d_in[0];
  const float* dec_embed = (const float*)d_in[1];
  const float* eWih_f = (const float*)d_in[2];
  const float* eWhh_f = (const float*)d_in[3];
  const float* ebih_f = (const float*)d_in[4];
  const float* ebhh_f = (const float*)d_in[5];
  const float* eWih_b = (const float*)d_in[6];
  const float* eWhh_b = (const float*)d_in[7];
  const float* ebih_b = (const float*)d_in[8];
  const float* ebhh_b = (const float*)d_in[9];
  const float* dWih = (const float*)d_in[10];
  const float* dWhh = (const float*)d_in[11];
  const float* dbih = (const float*)d_in[12];
  const float* dbhh = (const float*)d_in[13];
  const float* WsW  = (const float*)d_in[14];
  const float* Wsb  = (const float*)d_in[15];
  const int* src_tokens  = (const int*)d_in[16];
  const int* src_lengths = (const int*)d_in[17];
  const int* tgt_tokens  = (const int*)d_in[18];
  float* W = (float*)d_ws;

  size_t o = 0;
  auto alloc = [&](size_t n) { size_t r = o; o += (n + 63) & ~(size_t)63; return r; };
  // zeroed region first (one memset): henc0, cenc, wa, rowsum
  const size_t henc0 = alloc(2 * BB * 512);
  const size_t cenc  = alloc(2 * BB * 512);
  const size_t waoff = alloc(BB * 1024);
  const size_t rsum  = alloc(BB * TT);
  const size_t zbytes = o * sizeof(float);
  const size_t henc1 = alloc(2 * BB * 512);
  const size_t hdec0 = alloc(BB * 1024);
  const size_t hdec1 = alloc(BB * 1024);
  const size_t cdec  = alloc(BB * 1024);
  const size_t tlog  = alloc(BB * TT);
  const size_t xg    = alloc((size_t)2 * 1536 * 2048);
  const size_t pre   = alloc((size_t)1536 * 4096);
  const size_t outbuf= alloc((size_t)2 * BB * SS * 512);
  const size_t senc  = alloc((size_t)1536 * 1024);
  const size_t whhT  = alloc((size_t)2 * 512 * 2048);
  const size_t dWT   = alloc((size_t)2048 * 4096);
  const size_t embbf = alloc(786432 / 2);        // bf16 counted in float units
  const size_t embRbf= alloc(786432 / 2);
  const size_t dembbf= alloc(786432 / 2);
  const size_t wihfbf= alloc(1048576 / 2);
  const size_t wihbbf= alloc(1048576 / 2);
  const size_t dwihebf = alloc((size_t)4096 * 512 / 2);
  const size_t outsbf  = alloc((size_t)1536 * 2048 / 2);

  (void)hipMemsetAsync(W, 0, zbytes, stream);

  embed_src_kernel<<<3072, 256, 0, stream>>>(enc_embed, src_tokens, src_lengths,
                                             (__bf16*)(W + embbf), (__bf16*)(W + embRbf));
  embed_tgt_kernel<<<3072, 256, 0, stream>>>(dec_embed, tgt_tokens, (__bf16*)(W + dembbf));
  f2bf_kernel<<<1024, 256, 0, stream>>>(eWih_f, (__bf16*)(W + wihfbf), 262144);
  f2bf_kernel<<<1024, 256, 0, stream>>>(eWih_b, (__bf16*)(W + wihbbf), 262144);
  f2bf_slice_kernel<<<8192, 256, 0, stream>>>(dWih, (__bf16*)(W + dwihebf), 4096, 512, 1536, 1024);
  transpose_kernel<<<dim3(16, 64), 256, 0, stream>>>(eWhh_f, W + whhT, 2048, 512, 512, 0);
  transpose_kernel<<<dim3(16, 64), 256, 0, stream>>>(eWhh_b, W + whhT + (size_t)512 * 2048, 2048, 512, 512, 0);
  transpose_kernel<<<dim3(32, 128), 256, 0, stream>>>(dWih, W + dWT, 4096, 1024, 1536, 0);
  transpose_kernel<<<dim3(32, 128), 256, 0, stream>>>(dWhh, W + dWT + (size_t)1024 * 4096, 4096, 1024, 1024, 0);

  gemm_bf16_kernel<<<dim3(12, 16), 256, 0, stream>>>((__bf16*)(W + embbf), (__bf16*)(W + wihfbf),
                                                     ebih_f, ebhh_f, W + xg, 512, 2048);
  gemm_bf16_kernel<<<dim3(12, 16), 256, 0, stream>>>((__bf16*)(W + embRbf), (__bf16*)(W + wihbbf),
                                                     ebih_b, ebhh_b, W + xg + (size_t)1536 * 2048, 512, 2048);
  gemm_bf16_kernel<<<dim3(12, 32), 256, 0, stream>>>((__bf16*)(W + dembbf), (__bf16*)(W + dwihebf),
                                                     dbih, dbhh, W + pre, 512, 4096);

  for (int t = 0; t < SS; t++) {
    const float* hin = W + ((t & 1) ? henc1 : henc0);
    float* hout = W + ((t & 1) ? henc0 : henc1);
    enc_step_kernel<<<dim3(32, 4, 2), 256, 0, stream>>>(W + xg, W + whhT, hin, hout,
                                                        W + cenc, W + outbuf, src_lengths, t);
  }
  compose_kernel<<<6400, 256, 0, stream>>>(W + outbuf, W + outbuf + (size_t)BB * SS * 512,
                                           W + henc0, W + cenc, src_lengths,
                                           W + senc, W + hdec0, W + cdec);
  for (int t = 0; t < TT; t++) {
    const float* hin = W + ((t & 1) ? hdec1 : hdec0);
    float* hout = W + ((t & 1) ? hdec0 : hdec1);
    dec_step_kernel<<<dim3(64, 4), 256, 0, stream>>>(W + pre, W + dWT, W + waoff, hin, hout,
                                                     W + cdec, t);
    dec_attn_kernel<<<32, 256, 0, stream>>>(hout, W + senc, src_lengths, W + waoff,
                                            (__bf16*)(W + outsbf), t);
  }
  logits_kernel<<<dim3(12, 250), 256, 0, stream>>>((const __bf16*)(W + outsbf), WsW, Wsb, W + rsum);
  tgt_logit_kernel<<<1536, 256, 0, stream>>>((const __bf16*)(W + outsbf), WsW, Wsb, tgt_tokens, W + tlog);
  final_kernel<<<1, 256, 0, stream>>>(W + rsum, W + tlog, tgt_tokens, (float*)d_out);
}

// Round 2
// 5654.406 us; speedup vs baseline: 2.5269x; 2.5269x over previous
//
#include <hip/hip_runtime.h>
#include <hip/hip_bf16.h>
#include <math.h>

#define EE   512
#define HJ   1024
#define VV   32000
#define BB   32
#define SS   48
#define TT   48

typedef float f32x4 __attribute__((ext_vector_type(4)));
typedef __bf16 bf16x8 __attribute__((ext_vector_type(8)));
typedef __bf16 bf16x4 __attribute__((ext_vector_type(4)));

// ---------------------------------------------------------------- grid barrier
// Monotonic counter barrier. All 256 blocks are co-resident (grid == CU count,
// 1 block/CU by LDS), so spinning is safe. Device-scope atomics cross XCDs.
__device__ __forceinline__ void gsync(int* cnt, int target) {
  __syncthreads();
  if (threadIdx.x == 0) {
    __threadfence();
    __hip_atomic_fetch_add(cnt, 1, __ATOMIC_ACQ_REL, __HIP_MEMORY_SCOPE_AGENT);
    while (__hip_atomic_load(cnt, __ATOMIC_ACQUIRE, __HIP_MEMORY_SCOPE_AGENT) < target)
      __builtin_amdgcn_s_sleep(4);
    __threadfence();
  }
  __syncthreads();
}

// ---------------------------------------------------------------- embeddings
__global__ void embed_src_kernel(const float* __restrict__ enc_embed,
                                 const int* __restrict__ src_tokens,
                                 const int* __restrict__ src_lengths,
                                 __bf16* __restrict__ emb, __bf16* __restrict__ embR) {
  int idx = blockIdx.x * 256 + threadIdx.x;
  if (idx >= BB * SS * EE) return;
  int e = idx & (EE - 1);
  int bs = idx >> 9;
  int b = bs / SS, s = bs % SS;
  int tok = src_tokens[b * SS + s];
  emb[idx] = (__bf16)enc_embed[(size_t)tok * EE + e];
  int len = src_lengths[b];
  int rs = len - 1 - s; if (rs < 0) rs = 0;
  int tokr = src_tokens[b * SS + rs];
  embR[idx] = (__bf16)enc_embed[(size_t)tokr * EE + e];
}

__global__ void embed_tgt_kernel(const float* __restrict__ dec_embed,
                                 const int* __restrict__ tgt_tokens,
                                 __bf16* __restrict__ demb) {
  int idx = blockIdx.x * 256 + threadIdx.x;
  if (idx >= BB * TT * EE) return;
  int e = idx & (EE - 1);
  int bt = idx >> 9;
  int b = bt / TT, t = bt % TT;
  int tok = tgt_tokens[b * (TT + 1) + t];
  demb[idx] = (__bf16)dec_embed[(size_t)tok * EE + e];
}

// ---------------------------------------------------------------- converts
__global__ void f2bf_kernel(const float* __restrict__ src, __bf16* __restrict__ dst, int n4) {
  int i = blockIdx.x * 256 + threadIdx.x;
  if (i >= n4) return;
  float4 v = ((const float4*)src)[i];
  bf16x4 p = {(__bf16)v.x, (__bf16)v.y, (__bf16)v.z, (__bf16)v.w};
  ((bf16x4*)dst)[i] = p;
}

__global__ void f2bf_slice_kernel(const float* __restrict__ src, __bf16* __restrict__ dst,
                                  int rows, int cols, int ld, int c0) {
  int idx = blockIdx.x * 256 + threadIdx.x;
  if (idx >= rows * cols) return;
  int r = idx / cols, cc = idx % cols;
  dst[idx] = (__bf16)src[(size_t)r * ld + c0 + cc];
}

// Wd[r][k]: k<1024 -> dWih[r][k] (wa cols), else dWhh[r][k-1024]
__global__ void wdec_build_kernel(const float* __restrict__ dWih, const float* __restrict__ dWhh,
                                  __bf16* __restrict__ Wd) {
  int idx = blockIdx.x * 256 + threadIdx.x;
  if (idx >= 4096 * 2048) return;
  int r = idx >> 11, k = idx & 2047;
  float v = (k < 1024) ? dWih[(size_t)r * 1536 + k] : dWhh[(size_t)r * 1024 + (k - 1024)];
  Wd[idx] = (__bf16)v;
}

// ---------------------------------------------------------------- bf16 MFMA GEMM (NT)
__global__ __launch_bounds__(256) void gemm_bf16_kernel(
    const __bf16* __restrict__ A, const __bf16* __restrict__ Bm,
    const float* __restrict__ bias1, const float* __restrict__ bias2,
    float* __restrict__ C, int K, int N) {
  const int m0 = blockIdx.x * 128;
  const int n0 = blockIdx.y * 128;
  __shared__ __bf16 As[128 * 40];
  __shared__ __bf16 Bs[128 * 40];
  const int tid = threadIdx.x;
  const int lane = tid & 63, wave = tid >> 6;
  const int wm = (wave >> 1) * 64, wn = (wave & 1) * 64;
  const f32x4 zero = {0.f, 0.f, 0.f, 0.f};
  f32x4 acc[4][4];
  for (int i = 0; i < 4; i++) for (int j = 0; j < 4; j++) acc[i][j] = zero;
  const int r = tid >> 2, seg = tid & 3;
  const int mr = lane & 15, q8 = (lane >> 4) * 8;
  for (int k0 = 0; k0 < K; k0 += 32) {
    *(float4*)&As[r * 40 + seg * 8]        = *(const float4*)&A[(size_t)(m0 + r) * K + k0 + seg * 8];
    *(float4*)&As[(r + 64) * 40 + seg * 8] = *(const float4*)&A[(size_t)(m0 + r + 64) * K + k0 + seg * 8];
    *(float4*)&Bs[r * 40 + seg * 8]        = *(const float4*)&Bm[(size_t)(n0 + r) * K + k0 + seg * 8];
    *(float4*)&Bs[(r + 64) * 40 + seg * 8] = *(const float4*)&Bm[(size_t)(n0 + r + 64) * K + k0 + seg * 8];
    __syncthreads();
    bf16x8 af[4], bfr[4];
    for (int i = 0; i < 4; i++) af[i]  = *(const bf16x8*)&As[(wm + i * 16 + mr) * 40 + q8];
    for (int i = 0; i < 4; i++) bfr[i] = *(const bf16x8*)&Bs[(wn + i * 16 + mr) * 40 + q8];
    for (int i = 0; i < 4; i++)
      for (int j = 0; j < 4; j++)
        acc[i][j] = __builtin_amdgcn_mfma_f32_16x16x32_bf16(af[i], bfr[j], acc[i][j], 0, 0, 0);
    __syncthreads();
  }
  const int col = lane & 15, q = lane >> 4;
  for (int i = 0; i < 4; i++) {
    int rowg = m0 + wm + i * 16 + q * 4;
    for (int j = 0; j < 4; j++) {
      int cg = n0 + wn + j * 16 + col;
      float bb = bias1[cg] + bias2[cg];
      for (int rr = 0; rr < 4; rr++)
        C[(size_t)(rowg + rr) * N + cg] = acc[i][j][rr] + bb;
    }
  }
}

// ---------------------------------------------------------------- logits MFMA + exp-sum epilogue
__global__ __launch_bounds__(256) void logits_kernel(
    const __bf16* __restrict__ A, const float* __restrict__ WsW,
    const float* __restrict__ Wsb, float* __restrict__ rowsum) {
  const int m0 = blockIdx.x * 128;
  const int n0 = blockIdx.y * 128;
  __shared__ __bf16 As[128 * 40];
  __shared__ __bf16 Bs[128 * 40];
  const int tid = threadIdx.x;
  const int lane = tid & 63, wave = tid >> 6;
  const int wm = (wave >> 1) * 64, wn = (wave & 1) * 64;
  const f32x4 zero = {0.f, 0.f, 0.f, 0.f};
  f32x4 acc[4][4];
  for (int i = 0; i < 4; i++) for (int j = 0; j < 4; j++) acc[i][j] = zero;
  const int r = tid >> 2, seg = tid & 3;
  const int rowb = tid >> 1, koff = (tid & 1) * 16;
  const int mr = lane & 15, q8 = (lane >> 4) * 8;
  for (int k0 = 0; k0 < 2048; k0 += 32) {
    *(float4*)&As[r * 40 + seg * 8]        = *(const float4*)&A[(size_t)(m0 + r) * 2048 + k0 + seg * 8];
    *(float4*)&As[(r + 64) * 40 + seg * 8] = *(const float4*)&A[(size_t)(m0 + r + 64) * 2048 + k0 + seg * 8];
    const float* gb = WsW + (size_t)(n0 + rowb) * 2048 + k0 + koff;
    float4 v0 = *(const float4*)(gb);
    float4 v1 = *(const float4*)(gb + 4);
    float4 v2 = *(const float4*)(gb + 8);
    float4 v3 = *(const float4*)(gb + 12);
    bf16x8 p0 = {(__bf16)v0.x,(__bf16)v0.y,(__bf16)v0.z,(__bf16)v0.w,
                 (__bf16)v1.x,(__bf16)v1.y,(__bf16)v1.z,(__bf16)v1.w};
    bf16x8 p1 = {(__bf16)v2.x,(__bf16)v2.y,(__bf16)v2.z,(__bf16)v2.w,
                 (__bf16)v3.x,(__bf16)v3.y,(__bf16)v3.z,(__bf16)v3.w};
    *(bf16x8*)&Bs[rowb * 40 + koff]     = p0;
    *(bf16x8*)&Bs[rowb * 40 + koff + 8] = p1;
    __syncthreads();
    bf16x8 af[4], bfr[4];
    for (int i = 0; i < 4; i++) af[i]  = *(const bf16x8*)&As[(wm + i * 16 + mr) * 40 + q8];
    for (int i = 0; i < 4; i++) bfr[i] = *(const bf16x8*)&Bs[(wn + i * 16 + mr) * 40 + q8];
    for (int i = 0; i < 4; i++)
      for (int j = 0; j < 4; j++)
        acc[i][j] = __builtin_amdgcn_mfma_f32_16x16x32_bf16(af[i], bfr[j], acc[i][j], 0, 0, 0);
    __syncthreads();
  }
  const int col = lane & 15, q = lane >> 4;
  for (int i = 0; i < 4; i++) {
    float s0 = 0, s1 = 0, s2 = 0, s3 = 0;
    for (int j = 0; j < 4; j++) {
      int cg = n0 + wn + j * 16 + col;
      float bb = Wsb[cg];
      s0 += expf(acc[i][j][0] + bb);
      s1 += expf(acc[i][j][1] + bb);
      s2 += expf(acc[i][j][2] + bb);
      s3 += expf(acc[i][j][3] + bb);
    }
    for (int off = 1; off < 16; off <<= 1) {
      s0 += __shfl_xor(s0, off, 64);
      s1 += __shfl_xor(s1, off, 64);
      s2 += __shfl_xor(s2, off, 64);
      s3 += __shfl_xor(s3, off, 64);
    }
    if (col == 0) {
      int rowg = m0 + wm + i * 16 + q * 4;
      atomicAdd(&rowsum[rowg],     s0);
      atomicAdd(&rowsum[rowg + 1], s1);
      atomicAdd(&rowsum[rowg + 2], s2);
      atomicAdd(&rowsum[rowg + 3], s3);
    }
  }
}

// ---------------------------------------------------------------- persistent encoder
// 256 blocks: block = (dir<<7) | (u0/4). Owns 4 units (16 gate rows), weights in LDS.
// h ping-pong in global (bf16). 1 grid sync per timestep.
__global__ __launch_bounds__(256) void enc_persistent(
    const __bf16* __restrict__ Wenc,   // [2][2048][512] bf16
    const float* __restrict__ xg,      // [2][1536][2048]
    const int* __restrict__ lens,
    __bf16* __restrict__ g_h,          // [2dir][2buf][32*512] bf16 (buf0 zeroed)
    float* __restrict__ cenc,          // [2][32][512]
    __bf16* __restrict__ ob,           // [2][1536][512] masked outputs
    int* __restrict__ cnt) {
  const int bk = blockIdx.x;
  const int dir = bk >> 7;
  const int u0 = (bk & 127) * 4;
  const int tid = threadIdx.x;
  const int lane = tid & 63, wave = tid >> 6;
  __shared__ __bf16 Wl[16 * 520];
  __shared__ float gsc[4 * 512];
  __shared__ float cl[128], hloc[128];
  {
    int row = tid >> 4, t16 = tid & 15;
    int g = row >> 2, du = row & 3;
    const __bf16* src = Wenc + ((size_t)dir * 2048 + g * 512 + u0 + du) * 512;
    for (int c = t16 * 32, e = t16 * 32 + 32; c < e; c += 8)
      *(bf16x8*)&Wl[row * 520 + c] = *(const bf16x8*)&src[c];
  }
  if (tid < 128) { cl[tid] = 0.f; hloc[tid] = 0.f; }
  __syncthreads();
  __bf16* ghd = g_h + dir * 32768;
  __bf16* obd = ob + (size_t)dir * (1536 * 512);
  const float* xgd = xg + (size_t)dir * 1536 * 2048;
  const int nr = lane & 15, q8 = (lane >> 4) * 8;
  int target = 0;
  for (int t = 0; t < SS; t++) {
    const int cur = t & 1;
    const __bf16* hc = ghd + cur * 16384;
    __bf16* hnx = ghd + (cur ^ 1) * 16384;
    float xv[4];
    if (tid < 128) {
      int b = tid >> 2, du = tid & 3;
#pragma unroll
      for (int g = 0; g < 4; g++)
        xv[g] = xgd[((size_t)b * SS + t) * 2048 + g * 512 + u0 + du];
    }
    f32x4 acc0 = {0.f,0.f,0.f,0.f}, acc1 = {0.f,0.f,0.f,0.f};
    const int kb = wave * 128;
#pragma unroll
    for (int ks = 0; ks < 4; ks++) {
      int k0 = kb + ks * 32;
      bf16x8 bf_ = *(const bf16x8*)&Wl[nr * 520 + k0 + q8];
      bf16x8 a0 = *(const bf16x8*)&hc[nr * 512 + k0 + q8];
      bf16x8 a1 = *(const bf16x8*)&hc[(nr + 16) * 512 + k0 + q8];
      acc0 = __builtin_amdgcn_mfma_f32_16x16x32_bf16(a0, bf_, acc0, 0, 0, 0);
      acc1 = __builtin_amdgcn_mfma_f32_16x16x32_bf16(a1, bf_, acc1, 0, 0, 0);
    }
#pragma unroll
    for (int rg = 0; rg < 4; rg++) {
      int m = (lane >> 4) * 4 + rg;
      gsc[wave * 512 + m * 16 + nr]       = acc0[rg];
      gsc[wave * 512 + 256 + m * 16 + nr] = acc1[rg];
    }
    __syncthreads();
    if (tid < 128) {
      int b = tid >> 2, du = tid & 3;
      float gt[4];
#pragma unroll
      for (int g = 0; g < 4; g++) {
        int base = (b >> 4) * 256 + (b & 15) * 16 + g * 4 + du;
        gt[g] = xv[g] + gsc[base] + gsc[512 + base] + gsc[1024 + base] + gsc[1536 + base];
      }
      bool m_ = t < lens[b];
      float cold = cl[tid], hold = hloc[tid];
      float si = 1.f / (1.f + __expf(-gt[0])), sf = 1.f / (1.f + __expf(-gt[1]));
      float so = 1.f / (1.f + __expf(-gt[3]));
      float cn = sf * cold + si * tanhf(gt[2]);
      float hv = so * tanhf(cn);
      float cne = m_ ? cn : cold;
      float hne = m_ ? hv : hold;
      cl[tid] = cne; hloc[tid] = hne;
      hnx[b * 512 + u0 + du] = (__bf16)hne;
      obd[((size_t)b * SS + t) * 512 + u0 + du] = m_ ? (__bf16)hv : (__bf16)0.f;
    }
    target += 256;
    gsync(cnt, target);
  }
  if (tid < 128) {
    int b = tid >> 2, du = tid & 3;
    cenc[(size_t)dir * 16384 + b * 512 + u0 + du] = cl[tid];
  }
}

// ---------------------------------------------------------------- compose
// src_enc bf16, decoder x-buffer buf0 (wa=0, h=h0), cdec fp32.
__global__ void compose_kernel(const __bf16* __restrict__ ob, const __bf16* __restrict__ g_h,
                               const float* __restrict__ cenc, const int* __restrict__ lens,
                               __bf16* __restrict__ senc, __bf16* __restrict__ g_x0,
                               float* __restrict__ cdec) {
  int idx = blockIdx.x * 256 + threadIdx.x;
  const int N1 = 1536 * 1024;
  if (idx < N1) {
    int u = idx & 1023, bs = idx >> 10, b = bs / SS, s = bs - b * SS;
    __bf16 v;
    if (u < 512) v = ob[(size_t)bs * 512 + u];
    else {
      int len = lens[b];
      if (s < len) {
        int rs = len - 1 - s;
        v = ob[(size_t)(1536 * 512) + ((size_t)b * SS + rs) * 512 + (u - 512)];
      } else v = (__bf16)0.f;
    }
    senc[idx] = v;
  } else if (idx < N1 + 32 * 2048) {
    int k = idx - N1;
    int b = k >> 11, u = k & 2047;
    __bf16 v = (__bf16)0.f;
    if (u >= 1024) {
      int uu = u - 1024;
      v = (uu < 512) ? g_h[b * 512 + uu] : g_h[32768 + b * 512 + (uu - 512)];
    }
    g_x0[k] = v;
  } else if (idx < N1 + 32 * 2048 + 32 * 1024) {
    int k = idx - N1 - 32 * 2048;
    int b = k >> 10, u = k & 1023;
    cdec[k] = (u < 512) ? cenc[b * 512 + u] : cenc[16384 + b * 512 + (u - 512)];
  }
}

// ---------------------------------------------------------------- persistent decoder
// 256 blocks, block bk owns 4 units (16 gate rows, 64KB LDS bf16 weights).
// Per step: gates MFMA + cell -> sync -> (redundant per-block align+softmax) + wa -> sync.
__global__ __launch_bounds__(256) void dec_persistent(
    const __bf16* __restrict__ Wd,     // [4096][2048] bf16
    const float* __restrict__ pre,     // [1536][4096]
    const __bf16* __restrict__ senc,   // [1536][1024] bf16
    const int* __restrict__ lens,
    const float* __restrict__ cdec,    // [32][1024]
    __bf16* __restrict__ g_x,          // [2][32][2048] bf16 (buf0 = wa0|h0)
    __bf16* __restrict__ outs,         // [1536][2048] bf16
    int* __restrict__ cnt) {
  const int bk = blockIdx.x;
  const int u0 = bk * 4;
  const int tid = threadIdx.x, lane = tid & 63, wave = tid >> 6;
  __shared__ __bf16 Wl[16 * 2056];
  __shared__ float gsc[4 * 512];
  __shared__ float cl[128];
  __shared__ float asm_l[48];
  {
    int row = tid >> 4, t16 = tid & 15;
    int g = row >> 2, du = row & 3;
    const __bf16* src = Wd + (size_t)(g * 1024 + u0 + du) * 2048;
    for (int c = t16 * 128, e = t16 * 128 + 128; c < e; c += 8)
      *(bf16x8*)&Wl[row * 2056 + c] = *(const bf16x8*)&src[c];
  }
  if (tid < 128) cl[tid] = cdec[(tid >> 2) * 1024 + u0 + (tid & 3)];
  __syncthreads();
  const int nr = lane & 15, q8 = (lane >> 4) * 8;
  const int bC = bk >> 3, j0 = (bk & 7) * 128;
  int target = 0;
  for (int t = 0; t < TT; t++) {
    const int cur = t & 1;
    const __bf16* xc = g_x + cur * (32 * 2048);
    __bf16* xn = g_x + (cur ^ 1) * (32 * 2048);
    float xv[4];
    if (tid < 128) {
      int b = tid >> 2, du = tid & 3;
#pragma unroll
      for (int g = 0; g < 4; g++)
        xv[g] = pre[((size_t)b * TT + t) * 4096 + g * 1024 + u0 + du];
    }
    f32x4 acc0 = {0.f,0.f,0.f,0.f}, acc1 = {0.f,0.f,0.f,0.f};
    const int kb = wave * 512;
#pragma unroll
    for (int ks = 0; ks < 16; ks++) {
      int k0 = kb + ks * 32;
      bf16x8 bf_ = *(const bf16x8*)&Wl[nr * 2056 + k0 + q8];
      bf16x8 a0 = *(const bf16x8*)&xc[nr * 2048 + k0 + q8];
      bf16x8 a1 = *(const bf16x8*)&xc[(nr + 16) * 2048 + k0 + q8];
      acc0 = __builtin_amdgcn_mfma_f32_16x16x32_bf16(a0, bf_, acc0, 0, 0, 0);
      acc1 = __builtin_amdgcn_mfma_f32_16x16x32_bf16(a1, bf_, acc1, 0, 0, 0);
    }
#pragma unroll
    for (int rg = 0; rg < 4; rg++) {
      int m = (lane >> 4) * 4 + rg;
      gsc[wave * 512 + m * 16 + nr]       = acc0[rg];
      gsc[wave * 512 + 256 + m * 16 + nr] = acc1[rg];
    }
    __syncthreads();
    if (tid < 128) {
      int b = tid >> 2, du = tid & 3;
      float gt[4];
#pragma unroll
      for (int g = 0; g < 4; g++) {
        int base = (b >> 4) * 256 + (b & 15) * 16 + g * 4 + du;
        gt[g] = xv[g] + gsc[base] + gsc[512 + base] + gsc[1024 + base] + gsc[1536 + base];
      }
      float cold = cl[tid];
      float si = 1.f / (1.f + __expf(-gt[0])), sf = 1.f / (1.f + __expf(-gt[1]));
      float so = 1.f / (1.f + __expf(-gt[3]));
      float cn = sf * cold + si * tanhf(gt[2]);
      float hv = so * tanhf(cn);
      cl[tid] = cn;
      __bf16 hb = (__bf16)hv;
      xn[b * 2048 + 1024 + u0 + du] = hb;
      outs[((size_t)b * TT + t) * 2048 + 1024 + u0 + du] = hb;
    }
    target += 256;
    gsync(cnt, target);            // h(t) visible everywhere
    // ---- attention: each block computes align+softmax for its bC (8x redundant)
    {
      int len = lens[bC];
      const __bf16* hh = xn + bC * 2048 + 1024;
      bf16x8 h0 = *(const bf16x8*)&hh[lane * 16];
      bf16x8 h1 = *(const bf16x8*)&hh[lane * 16 + 8];
      float hf[16];
#pragma unroll
      for (int i = 0; i < 8; i++) { hf[i] = (float)h0[i]; hf[8 + i] = (float)h1[i]; }
      for (int si = 0; si < 12; si++) {
        int s = wave * 12 + si;
        if (s >= len) { if (lane == 0) asm_l[s] = -1e30f; continue; }
        const __bf16* se = senc + ((size_t)bC * SS + s) * 1024;
        bf16x8 s0 = *(const bf16x8*)&se[lane * 16];
        bf16x8 s1 = *(const bf16x8*)&se[lane * 16 + 8];
        float p = 0.f;
#pragma unroll
        for (int i = 0; i < 8; i++) p += (float)s0[i] * hf[i] + (float)s1[i] * hf[8 + i];
#pragma unroll
        for (int off = 32; off > 0; off >>= 1) p += __shfl_xor(p, off, 64);
        if (lane == 0) asm_l[s] = p;
      }
      __syncthreads();
      if (wave == 0) {
        float a = (lane < SS) ? asm_l[lane] : -1e30f;
        float mx = a;
#pragma unroll
        for (int off = 32; off > 0; off >>= 1) mx = fmaxf(mx, __shfl_xor(mx, off, 64));
        float p = (lane < SS) ? __expf(a - mx) : 0.f;
        float sm = p;
#pragma unroll
        for (int off = 32; off > 0; off >>= 1) sm += __shfl_xor(sm, off, 64);
        if (lane < SS) asm_l[lane] = p / sm;
      }
      __syncthreads();
      if (tid < 128) {
        int j = j0 + tid;
        const __bf16* sb = senc + (size_t)bC * SS * 1024 + j;
        float w = 0.f;
#pragma unroll 8
        for (int s = 0; s < SS; s++) w += asm_l[s] * (float)sb[s * 1024];
        __bf16 wb = (__bf16)w;
        xn[bC * 2048 + j] = wb;
        outs[((size_t)bC * TT + t) * 2048 + j] = wb;
      }
    }
    target += 256;
    gsync(cnt, target);            // wa(t) visible everywhere
  }
}

// ---------------------------------------------------------------- target logit per row
__global__ __launch_bounds__(256) void tgt_logit_kernel(
    const __bf16* __restrict__ outs_bf, const float* __restrict__ WsW,
    const float* __restrict__ Wsb, const int* __restrict__ tgt_tokens,
    float* __restrict__ tlogit) {
  const int r = blockIdx.x;
  const int b = r / TT, t = r % TT;
  const int tgt = tgt_tokens[b * (TT + 1) + t + 1];
  const __bf16* a = outs_bf + (size_t)r * 2048;
  const float* w = WsW + (size_t)tgt * 2048;
  const int tid = threadIdx.x;
  float p = 0;
  for (int k = tid; k < 2048; k += 256) p += (float)a[k] * w[k];
  for (int off = 32; off > 0; off >>= 1) p += __shfl_down(p, off, 64);
  __shared__ float red[4];
  if ((tid & 63) == 0) red[tid >> 6] = p;
  __syncthreads();
  if (tid == 0) tlogit[r] = red[0] + red[1] + red[2] + red[3] + Wsb[tgt];
}

// ---------------------------------------------------------------- final reduce
__global__ void final_kernel(const float* __restrict__ rowsum, const float* __restrict__ tlogit,
                             const int* __restrict__ tgt_tokens, float* __restrict__ out) {
  const int tid = threadIdx.x;
  float s = 0;
  for (int r = tid; r < BB * TT; r += 256) {
    int b = r / TT, t = r % TT;
    int tgt = tgt_tokens[b * (TT + 1) + t + 1];
    if (tgt != 0) s += logf(rowsum[r]) - tlogit[r];
  }
  for (int off = 32; off > 0; off >>= 1) s += __shfl_down(s, off, 64);
  __shared__ float red[4];
  if ((tid & 63) == 0) red[tid >> 6] = s;
  __syncthreads();
  if (tid == 0) out[0] = red[0] + red[1] + red[2] + red[3];
}

// ================================================================ host
extern "C" void kernel_launch(void* const* d_in, const int* in_sizes, int n_in,
                              void* d_out, int out_size, void* d_ws, size_t ws_size,
                              hipStream_t stream) {
  const float* enc_embed = (const float*)d_in[0];
  const float* dec_embed = (const float*)d_in[1];
  const float* eWih_f = (const float*)d_in[2];
  const float* eWhh_f = (const float*)d_in[3];
  const float* ebih_f = (const float*)d_in[4];
  const float* ebhh_f = (const float*)d_in[5];
  const float* eWih_b = (const float*)d_in[6];
  const float* eWhh_b = (const float*)d_in[7];
  const float* ebih_b = (const float*)d_in[8];
  const float* ebhh_b = (const float*)d_in[9];
  const float* dWih = (const float*)d_in[10];
  const float* dWhh = (const float*)d_in[11];
  const float* dbih = (const float*)d_in[12];
  const float* dbhh = (const float*)d_in[13];
  const float* WsW  = (const float*)d_in[14];
  const float* Wsb  = (const float*)d_in[15];
  const int* src_tokens  = (const int*)d_in[16];
  const int* src_lengths = (const int*)d_in[17];
  const int* tgt_tokens  = (const int*)d_in[18];
  float* W = (float*)d_ws;

  size_t o = 0;
  auto alloc = [&](size_t n) { size_t r = o; o += (n + 63) & ~(size_t)63; return r; };
  // ---- zeroed region: barrier counters, encoder h ping-pong (buf0 must be 0), rowsum
  const size_t cnts  = alloc(16);                      // [0]=enc cnt, [1]=dec cnt
  const size_t ghenc = alloc(32768);                   // 2dir*2buf*32*512 bf16 = 32768 floats
  const size_t rsum  = alloc(BB * TT);
  const size_t zbytes = o * sizeof(float);
  // ---- rest
  const size_t cenc  = alloc(2 * BB * 512);
  const size_t cdec  = alloc(BB * 1024);
  const size_t tlog  = alloc(BB * TT);
  const size_t xg    = alloc((size_t)2 * 1536 * 2048);
  const size_t pre   = alloc((size_t)1536 * 4096);
  const size_t obuf  = alloc((size_t)2 * 1536 * 512 / 2);   // bf16
  const size_t senc  = alloc((size_t)1536 * 1024 / 2);      // bf16
  const size_t gx    = alloc((size_t)2 * 32 * 2048 / 2);    // bf16
  const size_t wdec  = alloc((size_t)4096 * 2048 / 2);      // bf16
  const size_t wenc  = alloc((size_t)2 * 2048 * 512 / 2);   // bf16
  const size_t embbf = alloc(786432 / 2);
  const size_t embRbf= alloc(786432 / 2);
  const size_t dembbf= alloc(786432 / 2);
  const size_t wihfbf= alloc(1048576 / 2);
  const size_t wihbbf= alloc(1048576 / 2);
  const size_t dwihebf = alloc((size_t)4096 * 512 / 2);
  const size_t outsbf  = alloc((size_t)1536 * 2048 / 2);

  (void)hipMemsetAsync(W, 0, zbytes, stream);

  embed_src_kernel<<<3072, 256, 0, stream>>>(enc_embed, src_tokens, src_lengths,
                                             (__bf16*)(W + embbf), (__bf16*)(W + embRbf));
  embed_tgt_kernel<<<3072, 256, 0, stream>>>(dec_embed, tgt_tokens, (__bf16*)(W + dembbf));
  f2bf_kernel<<<1024, 256, 0, stream>>>(eWih_f, (__bf16*)(W + wihfbf), 262144);
  f2bf_kernel<<<1024, 256, 0, stream>>>(eWih_b, (__bf16*)(W + wihbbf), 262144);
  f2bf_kernel<<<1024, 256, 0, stream>>>(eWhh_f, (__bf16*)(W + wenc), 262144);
  f2bf_kernel<<<1024, 256, 0, stream>>>(eWhh_b, (__bf16*)(W + wenc) + 1048576, 262144);
  f2bf_slice_kernel<<<8192, 256, 0, stream>>>(dWih, (__bf16*)(W + dwihebf), 4096, 512, 1536, 1024);
  wdec_build_kernel<<<32768, 256, 0, stream>>>(dWih, dWhh, (__bf16*)(W + wdec));

  gemm_bf16_kernel<<<dim3(12, 16), 256, 0, stream>>>((__bf16*)(W + embbf), (__bf16*)(W + wihfbf),
                                                     ebih_f, ebhh_f, W + xg, 512, 2048);
  gemm_bf16_kernel<<<dim3(12, 16), 256, 0, stream>>>((__bf16*)(W + embRbf), (__bf16*)(W + wihbbf),
                                                     ebih_b, ebhh_b, W + xg + (size_t)1536 * 2048, 512, 2048);
  gemm_bf16_kernel<<<dim3(12, 32), 256, 0, stream>>>((__bf16*)(W + dembbf), (__bf16*)(W + dwihebf),
                                                     dbih, dbhh, W + pre, 512, 4096);

  enc_persistent<<<256, 256, 0, stream>>>((__bf16*)(W + wenc), W + xg, src_lengths,
                                          (__bf16*)(W + ghenc), W + cenc,
                                          (__bf16*)(W + obuf), (int*)(W + cnts));
  compose_kernel<<<6528, 256, 0, stream>>>((__bf16*)(W + obuf), (__bf16*)(W + ghenc),
                                           W + cenc, src_lengths,
                                           (__bf16*)(W + senc), (__bf16*)(W + gx), W + cdec);
  dec_persistent<<<256, 256, 0, stream>>>((__bf16*)(W + wdec), W + pre, (__bf16*)(W + senc),
                                          src_lengths, W + cdec, (__bf16*)(W + gx),
                                          (__bf16*)(W + outsbf), (int*)(W + cnts) + 1);

  logits_kernel<<<dim3(12, 250), 256, 0, stream>>>((const __bf16*)(W + outsbf), WsW, Wsb, W + rsum);
  tgt_logit_kernel<<<1536, 256, 0, stream>>>((const __bf16*)(W + outsbf), WsW, Wsb, tgt_tokens, W + tlog);
  final_kernel<<<1, 256, 0, stream>>>(W + rsum, W + tlog, tgt_tokens, (float*)d_out);
}

// Round 3
// 3395.158 us; speedup vs baseline: 4.2084x; 1.6654x over previous
//
#include <hip/hip_runtime.h>
#include <hip/hip_bf16.h>
#include <math.h>

#define EE   512
#define HJ   1024
#define VV   32000
#define BB   32
#define SS   48
#define TT   48

typedef float f32x4 __attribute__((ext_vector_type(4)));
typedef __bf16 bf16x8 __attribute__((ext_vector_type(8)));
typedef __bf16 bf16x4 __attribute__((ext_vector_type(4)));

// ---------------------------------------------------------------- grid barrier
// Decentralized: one flag per block on its own 64B line. RELAXED stores/polls
// (no per-poll L2 invalidate -- that was the 36us/barrier killer in R2);
// exactly one release fence before publish, one acquire fence after observe.
// grid must be 256 blocks of 256 threads (thread i polls block i's flag).
__device__ __forceinline__ void gbar(int* flags, int step) {
  __syncthreads();
  if (threadIdx.x == 0) {
    __threadfence();   // release: make this block's writes visible device-wide
    __hip_atomic_store(flags + blockIdx.x * 16, step, __ATOMIC_RELAXED,
                       __HIP_MEMORY_SCOPE_AGENT);
  }
  while (__hip_atomic_load(flags + threadIdx.x * 16, __ATOMIC_RELAXED,
                           __HIP_MEMORY_SCOPE_AGENT) < step)
    __builtin_amdgcn_s_sleep(1);
  __syncthreads();                       // all 256 flags observed by this block
  if (threadIdx.x == 0) __threadfence(); // acquire: invalidate stale L1/L2
  __syncthreads();
}

// ---------------------------------------------------------------- embeddings
__global__ void embed_src_kernel(const float* __restrict__ enc_embed,
                                 const int* __restrict__ src_tokens,
                                 const int* __restrict__ src_lengths,
                                 __bf16* __restrict__ emb, __bf16* __restrict__ embR) {
  int idx = blockIdx.x * 256 + threadIdx.x;
  if (idx >= BB * SS * EE) return;
  int e = idx & (EE - 1);
  int bs = idx >> 9;
  int b = bs / SS, s = bs % SS;
  int tok = src_tokens[b * SS + s];
  emb[idx] = (__bf16)enc_embed[(size_t)tok * EE + e];
  int len = src_lengths[b];
  int rs = len - 1 - s; if (rs < 0) rs = 0;
  int tokr = src_tokens[b * SS + rs];
  embR[idx] = (__bf16)enc_embed[(size_t)tokr * EE + e];
}

__global__ void embed_tgt_kernel(const float* __restrict__ dec_embed,
                                 const int* __restrict__ tgt_tokens,
                                 __bf16* __restrict__ demb) {
  int idx = blockIdx.x * 256 + threadIdx.x;
  if (idx >= BB * TT * EE) return;
  int e = idx & (EE - 1);
  int bt = idx >> 9;
  int b = bt / TT, t = bt % TT;
  int tok = tgt_tokens[b * (TT + 1) + t];
  demb[idx] = (__bf16)dec_embed[(size_t)tok * EE + e];
}

// ---------------------------------------------------------------- converts
__global__ void f2bf_kernel(const float* __restrict__ src, __bf16* __restrict__ dst, int n4) {
  int i = blockIdx.x * 256 + threadIdx.x;
  if (i >= n4) return;
  float4 v = ((const float4*)src)[i];
  bf16x4 p = {(__bf16)v.x, (__bf16)v.y, (__bf16)v.z, (__bf16)v.w};
  ((bf16x4*)dst)[i] = p;
}

__global__ void f2bf_slice_kernel(const float* __restrict__ src, __bf16* __restrict__ dst,
                                  int rows, int cols, int ld, int c0) {
  int idx = blockIdx.x * 256 + threadIdx.x;
  if (idx >= rows * cols) return;
  int r = idx / cols, cc = idx % cols;
  dst[idx] = (__bf16)src[(size_t)r * ld + c0 + cc];
}

// Wd[r][k]: k<1024 -> dWih[r][k] (wa cols), else dWhh[r][k-1024]
__global__ void wdec_build_kernel(const float* __restrict__ dWih, const float* __restrict__ dWhh,
                                  __bf16* __restrict__ Wd) {
  int idx = blockIdx.x * 256 + threadIdx.x;
  if (idx >= 4096 * 2048) return;
  int r = idx >> 11, k = idx & 2047;
  float v = (k < 1024) ? dWih[(size_t)r * 1536 + k] : dWhh[(size_t)r * 1024 + (k - 1024)];
  Wd[idx] = (__bf16)v;
}

// ---------------------------------------------------------------- bf16 MFMA GEMM (NT)
__global__ __launch_bounds__(256) void gemm_bf16_kernel(
    const __bf16* __restrict__ A, const __bf16* __restrict__ Bm,
    const float* __restrict__ bias1, const float* __restrict__ bias2,
    float* __restrict__ C, int K, int N) {
  const int m0 = blockIdx.x * 128;
  const int n0 = blockIdx.y * 128;
  __shared__ __bf16 As[128 * 40];
  __shared__ __bf16 Bs[128 * 40];
  const int tid = threadIdx.x;
  const int lane = tid & 63, wave = tid >> 6;
  const int wm = (wave >> 1) * 64, wn = (wave & 1) * 64;
  const f32x4 zero = {0.f, 0.f, 0.f, 0.f};
  f32x4 acc[4][4];
  for (int i = 0; i < 4; i++) for (int j = 0; j < 4; j++) acc[i][j] = zero;
  const int r = tid >> 2, seg = tid & 3;
  const int mr = lane & 15, q8 = (lane >> 4) * 8;
  for (int k0 = 0; k0 < K; k0 += 32) {
    *(float4*)&As[r * 40 + seg * 8]        = *(const float4*)&A[(size_t)(m0 + r) * K + k0 + seg * 8];
    *(float4*)&As[(r + 64) * 40 + seg * 8] = *(const float4*)&A[(size_t)(m0 + r + 64) * K + k0 + seg * 8];
    *(float4*)&Bs[r * 40 + seg * 8]        = *(const float4*)&Bm[(size_t)(n0 + r) * K + k0 + seg * 8];
    *(float4*)&Bs[(r + 64) * 40 + seg * 8] = *(const float4*)&Bm[(size_t)(n0 + r + 64) * K + k0 + seg * 8];
    __syncthreads();
    bf16x8 af[4], bfr[4];
    for (int i = 0; i < 4; i++) af[i]  = *(const bf16x8*)&As[(wm + i * 16 + mr) * 40 + q8];
    for (int i = 0; i < 4; i++) bfr[i] = *(const bf16x8*)&Bs[(wn + i * 16 + mr) * 40 + q8];
    for (int i = 0; i < 4; i++)
      for (int j = 0; j < 4; j++)
        acc[i][j] = __builtin_amdgcn_mfma_f32_16x16x32_bf16(af[i], bfr[j], acc[i][j], 0, 0, 0);
    __syncthreads();
  }
  const int col = lane & 15, q = lane >> 4;
  for (int i = 0; i < 4; i++) {
    int rowg = m0 + wm + i * 16 + q * 4;
    for (int j = 0; j < 4; j++) {
      int cg = n0 + wn + j * 16 + col;
      float bb = bias1[cg] + bias2[cg];
      for (int rr = 0; rr < 4; rr++)
        C[(size_t)(rowg + rr) * N + cg] = acc[i][j][rr] + bb;
    }
  }
}

// ---------------------------------------------------------------- logits MFMA + exp-sum epilogue
// BF=1: B is pre-converted bf16 [32000][2048]. BF=0: B is fp32, convert in staging.
template <int BF>
__global__ __launch_bounds__(256) void logits_kernel(
    const __bf16* __restrict__ A, const void* __restrict__ Braw,
    const float* __restrict__ Wsb, float* __restrict__ rowsum) {
  const int m0 = blockIdx.x * 128;
  const int n0 = blockIdx.y * 128;
  __shared__ __bf16 As[128 * 40];
  __shared__ __bf16 Bs[128 * 40];
  const int tid = threadIdx.x;
  const int lane = tid & 63, wave = tid >> 6;
  const int wm = (wave >> 1) * 64, wn = (wave & 1) * 64;
  const f32x4 zero = {0.f, 0.f, 0.f, 0.f};
  f32x4 acc[4][4];
  for (int i = 0; i < 4; i++) for (int j = 0; j < 4; j++) acc[i][j] = zero;
  const int r = tid >> 2, seg = tid & 3;
  const int rowb = tid >> 1, koff = (tid & 1) * 16;
  const int mr = lane & 15, q8 = (lane >> 4) * 8;
  for (int k0 = 0; k0 < 2048; k0 += 32) {
    *(float4*)&As[r * 40 + seg * 8]        = *(const float4*)&A[(size_t)(m0 + r) * 2048 + k0 + seg * 8];
    *(float4*)&As[(r + 64) * 40 + seg * 8] = *(const float4*)&A[(size_t)(m0 + r + 64) * 2048 + k0 + seg * 8];
    if (BF) {
      const __bf16* Bb = (const __bf16*)Braw;
      *(float4*)&Bs[r * 40 + seg * 8]        = *(const float4*)&Bb[(size_t)(n0 + r) * 2048 + k0 + seg * 8];
      *(float4*)&Bs[(r + 64) * 40 + seg * 8] = *(const float4*)&Bb[(size_t)(n0 + r + 64) * 2048 + k0 + seg * 8];
    } else {
      const float* gb = (const float*)Braw + (size_t)(n0 + rowb) * 2048 + k0 + koff;
      float4 v0 = *(const float4*)(gb);
      float4 v1 = *(const float4*)(gb + 4);
      float4 v2 = *(const float4*)(gb + 8);
      float4 v3 = *(const float4*)(gb + 12);
      bf16x8 p0 = {(__bf16)v0.x,(__bf16)v0.y,(__bf16)v0.z,(__bf16)v0.w,
                   (__bf16)v1.x,(__bf16)v1.y,(__bf16)v1.z,(__bf16)v1.w};
      bf16x8 p1 = {(__bf16)v2.x,(__bf16)v2.y,(__bf16)v2.z,(__bf16)v2.w,
                   (__bf16)v3.x,(__bf16)v3.y,(__bf16)v3.z,(__bf16)v3.w};
      *(bf16x8*)&Bs[rowb * 40 + koff]     = p0;
      *(bf16x8*)&Bs[rowb * 40 + koff + 8] = p1;
    }
    __syncthreads();
    bf16x8 af[4], bfr[4];
    for (int i = 0; i < 4; i++) af[i]  = *(const bf16x8*)&As[(wm + i * 16 + mr) * 40 + q8];
    for (int i = 0; i < 4; i++) bfr[i] = *(const bf16x8*)&Bs[(wn + i * 16 + mr) * 40 + q8];
    for (int i = 0; i < 4; i++)
      for (int j = 0; j < 4; j++)
        acc[i][j] = __builtin_amdgcn_mfma_f32_16x16x32_bf16(af[i], bfr[j], acc[i][j], 0, 0, 0);
    __syncthreads();
  }
  const int col = lane & 15, q = lane >> 4;
  for (int i = 0; i < 4; i++) {
    float s0 = 0, s1 = 0, s2 = 0, s3 = 0;
    for (int j = 0; j < 4; j++) {
      int cg = n0 + wn + j * 16 + col;
      float bb = Wsb[cg];
      s0 += expf(acc[i][j][0] + bb);
      s1 += expf(acc[i][j][1] + bb);
      s2 += expf(acc[i][j][2] + bb);
      s3 += expf(acc[i][j][3] + bb);
    }
    for (int off = 1; off < 16; off <<= 1) {
      s0 += __shfl_xor(s0, off, 64);
      s1 += __shfl_xor(s1, off, 64);
      s2 += __shfl_xor(s2, off, 64);
      s3 += __shfl_xor(s3, off, 64);
    }
    if (col == 0) {
      int rowg = m0 + wm + i * 16 + q * 4;
      atomicAdd(&rowsum[rowg],     s0);
      atomicAdd(&rowsum[rowg + 1], s1);
      atomicAdd(&rowsum[rowg + 2], s2);
      atomicAdd(&rowsum[rowg + 3], s3);
    }
  }
}

// ---------------------------------------------------------------- persistent encoder
__global__ __launch_bounds__(256) void enc_persistent(
    const __bf16* __restrict__ Wenc,   // [2][2048][512] bf16
    const float* __restrict__ xg,      // [2][1536][2048]
    const int* __restrict__ lens,
    __bf16* __restrict__ g_h,          // [2dir][2buf][32*512] bf16 (buf0 zeroed)
    float* __restrict__ cenc,          // [2][32][512]
    __bf16* __restrict__ ob,           // [2][1536][512] masked outputs
    int* __restrict__ flags) {
  const int bk = blockIdx.x;
  const int dir = bk >> 7;
  const int u0 = (bk & 127) * 4;
  const int tid = threadIdx.x;
  const int lane = tid & 63, wave = tid >> 6;
  __shared__ __bf16 Wl[16 * 520];
  __shared__ float gsc[4 * 512];
  __shared__ float cl[128], hloc[128];
  {
    int row = tid >> 4, t16 = tid & 15;
    int g = row >> 2, du = row & 3;
    const __bf16* src = Wenc + ((size_t)dir * 2048 + g * 512 + u0 + du) * 512;
    for (int c = t16 * 32, e = t16 * 32 + 32; c < e; c += 8)
      *(bf16x8*)&Wl[row * 520 + c] = *(const bf16x8*)&src[c];
  }
  if (tid < 128) { cl[tid] = 0.f; hloc[tid] = 0.f; }
  __syncthreads();
  __bf16* ghd = g_h + dir * 32768;
  __bf16* obd = ob + (size_t)dir * (1536 * 512);
  const float* xgd = xg + (size_t)dir * 1536 * 2048;
  const int nr = lane & 15, q8 = (lane >> 4) * 8;
  for (int t = 0; t < SS; t++) {
    const int cur = t & 1;
    const __bf16* hc = ghd + cur * 16384;
    __bf16* hnx = ghd + (cur ^ 1) * 16384;
    float xv[4];
    if (tid < 128) {
      int b = tid >> 2, du = tid & 3;
#pragma unroll
      for (int g = 0; g < 4; g++)
        xv[g] = xgd[((size_t)b * SS + t) * 2048 + g * 512 + u0 + du];
    }
    f32x4 acc0 = {0.f,0.f,0.f,0.f}, acc1 = {0.f,0.f,0.f,0.f};
    const int kb = wave * 128;
#pragma unroll
    for (int ks = 0; ks < 4; ks++) {
      int k0 = kb + ks * 32;
      bf16x8 bf_ = *(const bf16x8*)&Wl[nr * 520 + k0 + q8];
      bf16x8 a0 = *(const bf16x8*)&hc[nr * 512 + k0 + q8];
      bf16x8 a1 = *(const bf16x8*)&hc[(nr + 16) * 512 + k0 + q8];
      acc0 = __builtin_amdgcn_mfma_f32_16x16x32_bf16(a0, bf_, acc0, 0, 0, 0);
      acc1 = __builtin_amdgcn_mfma_f32_16x16x32_bf16(a1, bf_, acc1, 0, 0, 0);
    }
#pragma unroll
    for (int rg = 0; rg < 4; rg++) {
      int m = (lane >> 4) * 4 + rg;
      gsc[wave * 512 + m * 16 + nr]       = acc0[rg];
      gsc[wave * 512 + 256 + m * 16 + nr] = acc1[rg];
    }
    __syncthreads();
    if (tid < 128) {
      int b = tid >> 2, du = tid & 3;
      float gt[4];
#pragma unroll
      for (int g = 0; g < 4; g++) {
        int base = (b >> 4) * 256 + (b & 15) * 16 + g * 4 + du;
        gt[g] = xv[g] + gsc[base] + gsc[512 + base] + gsc[1024 + base] + gsc[1536 + base];
      }
      bool m_ = t < lens[b];
      float cold = cl[tid], hold = hloc[tid];
      float si = 1.f / (1.f + __expf(-gt[0])), sf = 1.f / (1.f + __expf(-gt[1]));
      float so = 1.f / (1.f + __expf(-gt[3]));
      float cn = sf * cold + si * tanhf(gt[2]);
      float hv = so * tanhf(cn);
      float cne = m_ ? cn : cold;
      float hne = m_ ? hv : hold;
      cl[tid] = cne; hloc[tid] = hne;
      hnx[b * 512 + u0 + du] = (__bf16)hne;
      obd[((size_t)b * SS + t) * 512 + u0 + du] = m_ ? (__bf16)hv : (__bf16)0.f;
    }
    gbar(flags, t + 1);
  }
  if (tid < 128) {
    int b = tid >> 2, du = tid & 3;
    cenc[(size_t)dir * 16384 + b * 512 + u0 + du] = cl[tid];
  }
}

// ---------------------------------------------------------------- compose
__global__ void compose_kernel(const __bf16* __restrict__ ob, const __bf16* __restrict__ g_h,
                               const float* __restrict__ cenc, const int* __restrict__ lens,
                               __bf16* __restrict__ senc, __bf16* __restrict__ g_x0,
                               float* __restrict__ cdec) {
  int idx = blockIdx.x * 256 + threadIdx.x;
  const int N1 = 1536 * 1024;
  if (idx < N1) {
    int u = idx & 1023, bs = idx >> 10, b = bs / SS, s = bs - b * SS;
    __bf16 v;
    if (u < 512) v = ob[(size_t)bs * 512 + u];
    else {
      int len = lens[b];
      if (s < len) {
        int rs = len - 1 - s;
        v = ob[(size_t)(1536 * 512) + ((size_t)b * SS + rs) * 512 + (u - 512)];
      } else v = (__bf16)0.f;
    }
    senc[idx] = v;
  } else if (idx < N1 + 32 * 2048) {
    int k = idx - N1;
    int b = k >> 11, u = k & 2047;
    __bf16 v = (__bf16)0.f;
    if (u >= 1024) {
      int uu = u - 1024;
      v = (uu < 512) ? g_h[b * 512 + uu] : g_h[32768 + b * 512 + (uu - 512)];
    }
    g_x0[k] = v;
  } else if (idx < N1 + 32 * 2048 + 32 * 1024) {
    int k = idx - N1 - 32 * 2048;
    int b = k >> 10, u = k & 1023;
    cdec[k] = (u < 512) ? cenc[b * 512 + u] : cenc[16384 + b * 512 + (u - 512)];
  }
}

// ---------------------------------------------------------------- persistent decoder
__global__ __launch_bounds__(256) void dec_persistent(
    const __bf16* __restrict__ Wd,     // [4096][2048] bf16
    const float* __restrict__ pre,     // [1536][4096]
    const __bf16* __restrict__ senc,   // [1536][1024] bf16
    const int* __restrict__ lens,
    const float* __restrict__ cdec,    // [32][1024]
    __bf16* __restrict__ g_x,          // [2][32][2048] bf16 (buf0 = wa0|h0)
    __bf16* __restrict__ outs,         // [1536][2048] bf16
    int* __restrict__ flags) {
  const int bk = blockIdx.x;
  const int u0 = bk * 4;
  const int tid = threadIdx.x, lane = tid & 63, wave = tid >> 6;
  __shared__ __bf16 Wl[16 * 2056];
  __shared__ float gsc[4 * 512];
  __shared__ float cl[128];
  __shared__ float asm_l[48];
  {
    int row = tid >> 4, t16 = tid & 15;
    int g = row >> 2, du = row & 3;
    const __bf16* src = Wd + (size_t)(g * 1024 + u0 + du) * 2048;
    for (int c = t16 * 128, e = t16 * 128 + 128; c < e; c += 8)
      *(bf16x8*)&Wl[row * 2056 + c] = *(const bf16x8*)&src[c];
  }
  if (tid < 128) cl[tid] = cdec[(tid >> 2) * 1024 + u0 + (tid & 3)];
  __syncthreads();
  const int nr = lane & 15, q8 = (lane >> 4) * 8;
  const int bC = bk >> 3, j0 = (bk & 7) * 128;
  for (int t = 0; t < TT; t++) {
    const int cur = t & 1;
    const __bf16* xc = g_x + cur * (32 * 2048);
    __bf16* xn = g_x + (cur ^ 1) * (32 * 2048);
    float xv[4];
    if (tid < 128) {
      int b = tid >> 2, du = tid & 3;
#pragma unroll
      for (int g = 0; g < 4; g++)
        xv[g] = pre[((size_t)b * TT + t) * 4096 + g * 1024 + u0 + du];
    }
    f32x4 acc0 = {0.f,0.f,0.f,0.f}, acc1 = {0.f,0.f,0.f,0.f};
    const int kb = wave * 512;
#pragma unroll
    for (int ks = 0; ks < 16; ks++) {
      int k0 = kb + ks * 32;
      bf16x8 bf_ = *(const bf16x8*)&Wl[nr * 2056 + k0 + q8];
      bf16x8 a0 = *(const bf16x8*)&xc[nr * 2048 + k0 + q8];
      bf16x8 a1 = *(const bf16x8*)&xc[(nr + 16) * 2048 + k0 + q8];
      acc0 = __builtin_amdgcn_mfma_f32_16x16x32_bf16(a0, bf_, acc0, 0, 0, 0);
      acc1 = __builtin_amdgcn_mfma_f32_16x16x32_bf16(a1, bf_, acc1, 0, 0, 0);
    }
#pragma unroll
    for (int rg = 0; rg < 4; rg++) {
      int m = (lane >> 4) * 4 + rg;
      gsc[wave * 512 + m * 16 + nr]       = acc0[rg];
      gsc[wave * 512 + 256 + m * 16 + nr] = acc1[rg];
    }
    __syncthreads();
    if (tid < 128) {
      int b = tid >> 2, du = tid & 3;
      float gt[4];
#pragma unroll
      for (int g = 0; g < 4; g++) {
        int base = (b >> 4) * 256 + (b & 15) * 16 + g * 4 + du;
        gt[g] = xv[g] + gsc[base] + gsc[512 + base] + gsc[1024 + base] + gsc[1536 + base];
      }
      float cold = cl[tid];
      float si = 1.f / (1.f + __expf(-gt[0])), sf = 1.f / (1.f + __expf(-gt[1]));
      float so = 1.f / (1.f + __expf(-gt[3]));
      float cn = sf * cold + si * tanhf(gt[2]);
      float hv = so * tanhf(cn);
      cl[tid] = cn;
      __bf16 hb = (__bf16)hv;
      xn[b * 2048 + 1024 + u0 + du] = hb;
      outs[((size_t)b * TT + t) * 2048 + 1024 + u0 + du] = hb;
    }
    gbar(flags, 2 * t + 1);            // h(t) visible everywhere
    // ---- attention: each block computes align+softmax for its bC (8x redundant)
    {
      int len = lens[bC];
      const __bf16* hh = xn + bC * 2048 + 1024;
      bf16x8 h0 = *(const bf16x8*)&hh[lane * 16];
      bf16x8 h1 = *(const bf16x8*)&hh[lane * 16 + 8];
      float hf[16];
#pragma unroll
      for (int i = 0; i < 8; i++) { hf[i] = (float)h0[i]; hf[8 + i] = (float)h1[i]; }
      for (int si = 0; si < 12; si++) {
        int s = wave * 12 + si;
        if (s >= len) { if (lane == 0) asm_l[s] = -1e30f; continue; }
        const __bf16* se = senc + ((size_t)bC * SS + s) * 1024;
        bf16x8 s0 = *(const bf16x8*)&se[lane * 16];
        bf16x8 s1 = *(const bf16x8*)&se[lane * 16 + 8];
        float p = 0.f;
#pragma unroll
        for (int i = 0; i < 8; i++) p += (float)s0[i] * hf[i] + (float)s1[i] * hf[8 + i];
#pragma unroll
        for (int off = 32; off > 0; off >>= 1) p += __shfl_xor(p, off, 64);
        if (lane == 0) asm_l[s] = p;
      }
      __syncthreads();
      if (wave == 0) {
        float a = (lane < SS) ? asm_l[lane] : -1e30f;
        float mx = a;
#pragma unroll
        for (int off = 32; off > 0; off >>= 1) mx = fmaxf(mx, __shfl_xor(mx, off, 64));
        float p = (lane < SS) ? __expf(a - mx) : 0.f;
        float sm = p;
#pragma unroll
        for (int off = 32; off > 0; off >>= 1) sm += __shfl_xor(sm, off, 64);
        if (lane < SS) asm_l[lane] = p / sm;
      }
      __syncthreads();
      if (tid < 128) {
        int j = j0 + tid;
        const __bf16* sb = senc + (size_t)bC * SS * 1024 + j;
        float w = 0.f;
#pragma unroll 8
        for (int s = 0; s < SS; s++) w += asm_l[s] * (float)sb[s * 1024];
        __bf16 wb = (__bf16)w;
        xn[bC * 2048 + j] = wb;
        outs[((size_t)bC * TT + t) * 2048 + j] = wb;
      }
    }
    gbar(flags, 2 * t + 2);            // wa(t) visible everywhere
  }
}

// ---------------------------------------------------------------- target logit per row
__global__ __launch_bounds__(256) void tgt_logit_kernel(
    const __bf16* __restrict__ outs_bf, const float* __restrict__ WsW,
    const float* __restrict__ Wsb, const int* __restrict__ tgt_tokens,
    float* __restrict__ tlogit) {
  const int r = blockIdx.x;
  const int b = r / TT, t = r % TT;
  const int tgt = tgt_tokens[b * (TT + 1) + t + 1];
  const __bf16* a = outs_bf + (size_t)r * 2048;
  const float* w = WsW + (size_t)tgt * 2048;
  const int tid = threadIdx.x;
  float p = 0;
  for (int k = tid; k < 2048; k += 256) p += (float)a[k] * w[k];
  for (int off = 32; off > 0; off >>= 1) p += __shfl_down(p, off, 64);
  __shared__ float red[4];
  if ((tid & 63) == 0) red[tid >> 6] = p;
  __syncthreads();
  if (tid == 0) tlogit[r] = red[0] + red[1] + red[2] + red[3] + Wsb[tgt];
}

// ---------------------------------------------------------------- final reduce
__global__ void final_kernel(const float* __restrict__ rowsum, const float* __restrict__ tlogit,
                             const int* __restrict__ tgt_tokens, float* __restrict__ out) {
  const int tid = threadIdx.x;
  float s = 0;
  for (int r = tid; r < BB * TT; r += 256) {
    int b = r / TT, t = r % TT;
    int tgt = tgt_tokens[b * (TT + 1) + t + 1];
    if (tgt != 0) s += logf(rowsum[r]) - tlogit[r];
  }
  for (int off = 32; off > 0; off >>= 1) s += __shfl_down(s, off, 64);
  __shared__ float red[4];
  if ((tid & 63) == 0) red[tid >> 6] = s;
  __syncthreads();
  if (tid == 0) out[0] = red[0] + red[1] + red[2] + red[3];
}

// ================================================================ host
extern "C" void kernel_launch(void* const* d_in, const int* in_sizes, int n_in,
                              void* d_out, int out_size, void* d_ws, size_t ws_size,
                              hipStream_t stream) {
  const float* enc_embed = (const float*)d_in[0];
  const float* dec_embed = (const float*)d_in[1];
  const float* eWih_f = (const float*)d_in[2];
  const float* eWhh_f = (const float*)d_in[3];
  const float* ebih_f = (const float*)d_in[4];
  const float* ebhh_f = (const float*)d_in[5];
  const float* eWih_b = (const float*)d_in[6];
  const float* eWhh_b = (const float*)d_in[7];
  const float* ebih_b = (const float*)d_in[8];
  const float* ebhh_b = (const float*)d_in[9];
  const float* dWih = (const float*)d_in[10];
  const float* dWhh = (const float*)d_in[11];
  const float* dbih = (const float*)d_in[12];
  const float* dbhh = (const float*)d_in[13];
  const float* WsW  = (const float*)d_in[14];
  const float* Wsb  = (const float*)d_in[15];
  const int* src_tokens  = (const int*)d_in[16];
  const int* src_lengths = (const int*)d_in[17];
  const int* tgt_tokens  = (const int*)d_in[18];
  float* W = (float*)d_ws;

  size_t o = 0;
  auto alloc = [&](size_t n) { size_t r = o; o += (n + 63) & ~(size_t)63; return r; };
  // ---- zeroed region: barrier flags, encoder h ping-pong (buf0 must be 0), rowsum
  const size_t flagsE = alloc(256 * 16);               // int flags, 64B apart
  const size_t flagsD = alloc(256 * 16);
  const size_t ghenc = alloc(32768);                   // 2dir*2buf*32*512 bf16 = 32768 floats
  const size_t rsum  = alloc(BB * TT);
  const size_t zbytes = o * sizeof(float);
  // ---- rest
  const size_t cenc  = alloc(2 * BB * 512);
  const size_t cdec  = alloc(BB * 1024);
  const size_t tlog  = alloc(BB * TT);
  const size_t xg    = alloc((size_t)2 * 1536 * 2048);
  const size_t pre   = alloc((size_t)1536 * 4096);
  const size_t obuf  = alloc((size_t)2 * 1536 * 512 / 2);   // bf16
  const size_t senc  = alloc((size_t)1536 * 1024 / 2);      // bf16
  const size_t gx    = alloc((size_t)2 * 32 * 2048 / 2);    // bf16
  const size_t wdec  = alloc((size_t)4096 * 2048 / 2);      // bf16
  const size_t wenc  = alloc((size_t)2 * 2048 * 512 / 2);   // bf16
  const size_t embbf = alloc(786432 / 2);
  const size_t embRbf= alloc(786432 / 2);
  const size_t dembbf= alloc(786432 / 2);
  const size_t wihfbf= alloc(1048576 / 2);
  const size_t wihbbf= alloc(1048576 / 2);
  const size_t dwihebf = alloc((size_t)4096 * 512 / 2);
  const size_t outsbf  = alloc((size_t)1536 * 2048 / 2);
  const size_t wsbf    = alloc((size_t)VV * 2048 / 2);      // bf16 Ws_W (131 MB)
  const bool wsbf_fit  = (o * sizeof(float)) <= ws_size;

  (void)hipMemsetAsync(W, 0, zbytes, stream);

  embed_src_kernel<<<3072, 256, 0, stream>>>(enc_embed, src_tokens, src_lengths,
                                             (__bf16*)(W + embbf), (__bf16*)(W + embRbf));
  embed_tgt_kernel<<<3072, 256, 0, stream>>>(dec_embed, tgt_tokens, (__bf16*)(W + dembbf));
  f2bf_kernel<<<1024, 256, 0, stream>>>(eWih_f, (__bf16*)(W + wihfbf), 262144);
  f2bf_kernel<<<1024, 256, 0, stream>>>(eWih_b, (__bf16*)(W + wihbbf), 262144);
  f2bf_kernel<<<1024, 256, 0, stream>>>(eWhh_f, (__bf16*)(W + wenc), 262144);
  f2bf_kernel<<<1024, 256, 0, stream>>>(eWhh_b, (__bf16*)(W + wenc) + 1048576, 262144);
  f2bf_slice_kernel<<<8192, 256, 0, stream>>>(dWih, (__bf16*)(W + dwihebf), 4096, 512, 1536, 1024);
  wdec_build_kernel<<<32768, 256, 0, stream>>>(dWih, dWhh, (__bf16*)(W + wdec));
  if (wsbf_fit)
    f2bf_kernel<<<64000, 256, 0, stream>>>(WsW, (__bf16*)(W + wsbf), VV * 2048 / 4);

  gemm_bf16_kernel<<<dim3(12, 16), 256, 0, stream>>>((__bf16*)(W + embbf), (__bf16*)(W + wihfbf),
                                                     ebih_f, ebhh_f, W + xg, 512, 2048);
  gemm_bf16_kernel<<<dim3(12, 16), 256, 0, stream>>>((__bf16*)(W + embRbf), (__bf16*)(W + wihbbf),
                                                     ebih_b, ebhh_b, W + xg + (size_t)1536 * 2048, 512, 2048);
  gemm_bf16_kernel<<<dim3(12, 32), 256, 0, stream>>>((__bf16*)(W + dembbf), (__bf16*)(W + dwihebf),
                                                     dbih, dbhh, W + pre, 512, 4096);

  enc_persistent<<<256, 256, 0, stream>>>((__bf16*)(W + wenc), W + xg, src_lengths,
                                          (__bf16*)(W + ghenc), W + cenc,
                                          (__bf16*)(W + obuf), (int*)(W + flagsE));
  compose_kernel<<<6528, 256, 0, stream>>>((__bf16*)(W + obuf), (__bf16*)(W + ghenc),
                                           W + cenc, src_lengths,
                                           (__bf16*)(W + senc), (__bf16*)(W + gx), W + cdec);
  dec_persistent<<<256, 256, 0, stream>>>((__bf16*)(W + wdec), W + pre, (__bf16*)(W + senc),
                                          src_lengths, W + cdec, (__bf16*)(W + gx),
                                          (__bf16*)(W + outsbf), (int*)(W + flagsD));

  if (wsbf_fit)
    logits_kernel<1><<<dim3(12, 250), 256, 0, stream>>>((const __bf16*)(W + outsbf),
                                                        (const void*)(W + wsbf), Wsb, W + rsum);
  else
    logits_kernel<0><<<dim3(12, 250), 256, 0, stream>>>((const __bf16*)(W + outsbf),
                                                        (const void*)WsW, Wsb, W + rsum);
  tgt_logit_kernel<<<1536, 256, 0, stream>>>((const __bf16*)(W + outsbf), WsW, Wsb, tgt_tokens, W + tlog);
  final_kernel<<<1, 256, 0, stream>>>(W + rsum, W + tlog, tgt_tokens, (float*)d_out);
}